// Round 12
// baseline (1424.098 us; speedup 1.0000x reference)
//
#include <hip/hip_runtime.h>
#include <math.h>

#define BN_EPS 1e-5f
#define NSEQ 4096
#define NB 8
#define LOG2E 1.4426950408889634f

typedef _Float16 h8 __attribute__((ext_vector_type(8)));
typedef __fp16 fp16x2 __attribute__((ext_vector_type(2)));
typedef float fx16 __attribute__((ext_vector_type(16)));
typedef float fx4 __attribute__((ext_vector_type(4)));
typedef float f2 __attribute__((ext_vector_type(2)));

static __device__ __forceinline__ unsigned pkrtz(float a, float b) {
    fp16x2 r = __builtin_amdgcn_cvt_pkrtz(a, b);
    return __builtin_bit_cast(unsigned, r);
}
// v_permlane32_swap: x' = [x_lo, y_lo], y' = [x_hi, y_hi]
static __device__ __forceinline__ void plswap(unsigned& x, unsigned& y) {
    asm volatile("v_permlane32_swap_b32 %0, %1" : "+v"(x), "+v"(y));
}

static __device__ __forceinline__ void gll16(const void* g, void* l) {
    __builtin_amdgcn_global_load_lds(
        (const __attribute__((address_space(1))) void*)g,
        (__attribute__((address_space(3))) void*)l, 16, 0, 0);
}

// ---------------- prep: transpose weights, fold BN ----------------
__global__ __launch_bounds__(256) void prep_kernel(
    const float* __restrict__ Wf, const float* __restrict__ Wg, const float* __restrict__ Wh,
    const float* __restrict__ bf_, const float* __restrict__ fs, const float* __restrict__ fb,
    const float* __restrict__ fm, const float* __restrict__ fv,
    const float* __restrict__ bg_, const float* __restrict__ gs, const float* __restrict__ gb,
    const float* __restrict__ gm, const float* __restrict__ gv,
    const float* __restrict__ bh_, const float* __restrict__ hs, const float* __restrict__ hb,
    const float* __restrict__ hm, const float* __restrict__ hv,
    float* __restrict__ WfT, float* __restrict__ WgT, float* __restrict__ WhT,
    float* __restrict__ Af, float* __restrict__ Bf, float* __restrict__ Ag, float* __restrict__ Bg,
    float* __restrict__ Ah, float* __restrict__ Bh)
{
    int idx = blockIdx.x * 256 + threadIdx.x;
    if (idx < 16384) {
        int co = idx & 63, ci = idx >> 6;
        WfT[idx] = Wf[co * 256 + ci];
    }
    if (idx < 8192) {
        int co = idx & 63, ci = idx >> 6;
        WgT[idx] = Wg[co * 128 + ci];
    }
    if (idx < 32768) {
        int co = idx & 255, ci = idx >> 8;
        WhT[idx] = Wh[co * 128 + ci];
    }
    if (idx < 64) {
        float A = fs[idx] / sqrtf(fv[idx] + BN_EPS);
        Af[idx] = A; Bf[idx] = (bf_[idx] - fm[idx]) * A + fb[idx];
    } else if (idx < 128) {
        int c = idx - 64;
        float A = gs[c] / sqrtf(gv[c] + BN_EPS);
        Ag[c] = A; Bg[c] = (bg_[c] - gm[c]) * A + gb[c];
    } else if (idx < 384) {
        int c = idx - 128;
        float A = hs[c] / sqrtf(hv[c] + BN_EPS);
        Ah[c] = A; Bh[c] = (bh_[c] - hm[c]) * A + hb[c];
    }
}

// ---------------- conv(1x1) + BN + exact GELU ----------------
// 256 thr = 32 n-slots x 8 co-groups; grid (NSEQ/32, NB) = 1024 -> 4 blk/CU.
// T14 async-STAGE: issue chunk c+1's x/W loads into regs BEFORE computing
// chunk c (latency hides under compute); write regs->LDS after the barrier.
template <int CIN, int COUT, bool TRANS, bool SCALE>
__global__ __launch_bounds__(256) void conv_bn_gelu(
    const float* __restrict__ in, const float* __restrict__ WT,
    const float* __restrict__ Avec, const float* __restrict__ Bvec,
    _Float16* __restrict__ out)
{
    constexpr int COG = COUT / 8;
    constexpr int NCH = CIN / 32;
    constexpr int WREG = (32 * COUT) / (4 * 256);   // float4 per thread per W chunk
    __shared__ float wl[32 * COUT];
    __shared__ float xl[32 * 40];   // [32 ci][32 n] padded to 40
    int tid = threadIdx.x;
    int ns = tid & 31, g = tid >> 5;
    int b = blockIdx.y;
    int n0 = blockIdx.x * 32;
    const float* inp = in + (size_t)b * CIN * NSEQ + n0;
    int xr = tid >> 3, xc4 = tid & 7;

    union { f2 a2[COG / 2]; float a[COG]; } acc;
#pragma unroll
    for (int c = 0; c < COG / 2; ++c) acc.a2[c] = (f2){0.f, 0.f};

    float4 xreg;
    float4 wreg[WREG];
    // prologue: load chunk 0 into regs, write to LDS
    xreg = *(const float4*)(inp + (size_t)xr * NSEQ + xc4 * 4);
#pragma unroll
    for (int w = 0; w < WREG; ++w)
        wreg[w] = ((const float4*)WT)[w * 256 + tid];
    *(float4*)(xl + xr * 40 + xc4 * 4) = xreg;
#pragma unroll
    for (int w = 0; w < WREG; ++w)
        ((float4*)wl)[w * 256 + tid] = wreg[w];
    __syncthreads();

#pragma unroll 1
    for (int ch = 0; ch < NCH; ++ch) {
        // issue next chunk's loads early (hide under compute)
        if (ch + 1 < NCH) {
            const float* inx = inp + (size_t)((ch + 1) * 32 + xr) * NSEQ;
            xreg = *(const float4*)(inx + xc4 * 4);
            const float4* wp = (const float4*)(WT + (size_t)(ch + 1) * 32 * COUT);
#pragma unroll
            for (int w = 0; w < WREG; ++w)
                wreg[w] = wp[w * 256 + tid];
        }
        // compute from LDS
#pragma unroll
        for (int ci = 0; ci < 32; ++ci) {
            float v = xl[ci * 40 + ns];
            const f2* wr = (const f2*)(wl + ci * COUT + g * COG);
            f2 vv = {v, v};
#pragma unroll
            for (int c = 0; c < COG / 2; ++c)
                acc.a2[c] = vv * wr[c] + acc.a2[c];   // v_pk_fma_f32
        }
        __syncthreads();   // all LDS reads of this chunk done
        if (ch + 1 < NCH) {
            *(float4*)(xl + xr * 40 + xc4 * 4) = xreg;
#pragma unroll
            for (int w = 0; w < WREG; ++w)
                ((float4*)wl)[w * 256 + tid] = wreg[w];
            __syncthreads();
        }
    }

    union { _Float16 hx[COG]; uint4 u4[COG / 8]; } ob;
#pragma unroll
    for (int c = 0; c < COG; ++c) {
        int co = g * COG + c;
        float y = fmaf(acc.a[c], Avec[co], Bvec[co]);
        float gel = 0.5f * y * (1.f + erff(y * 0.70710678118654752f));
        if (SCALE) gel *= LOG2E;
        if constexpr (TRANS) {
            ob.hx[c] = (_Float16)gel;
        } else {
            out[((size_t)b * COUT + co) * NSEQ + n0 + ns] = (_Float16)gel;
        }
    }
    if constexpr (TRANS) {
        _Float16* op = out + ((size_t)b * NSEQ + n0 + ns) * 64 + g * COG;
#pragma unroll
        for (int u = 0; u < COG / 8; ++u)
            *((uint4*)op + u) = ob.u4[u];
    }
}

// ---------------- flash attention (R9/R10 proven version, unchanged) ----------------
// fT,gT: [B][N][64] fp16 (gT pre-scaled by log2e) ; hV: [B][256][N] fp16
// grid 512: b=blk&7 (XCD-pinned), ib=(blk>>3)&31, chalf=blk>>8 (128 ch each).
// LDS 48KB: K 8KB x2 + V(128ch) 16KB x2, double-buffered, swizzled source.
__global__ __launch_bounds__(256, 2) void attn_kernel(
    const _Float16* __restrict__ fT, const _Float16* __restrict__ gT,
    const _Float16* __restrict__ hV, const float* __restrict__ q,
    const float* __restrict__ gammap, float* __restrict__ out)
{
    __shared__ __align__(16) char smem[49152];

    int tid = threadIdx.x;
    int lane = tid & 63;
    int wv = tid >> 6;
    int l31 = lane & 31;
    int hh = lane >> 5;
    int b = blockIdx.x & 7;
    int ib = (blockIdx.x >> 3) & 31;
    int chalf = blockIdx.x >> 8;
    int i0 = ib * 128 + wv * 32;

    float gamma = gammap[0];
    const _Float16* fTb = fT + (size_t)b * NSEQ * 64;
    const _Float16* hVb = hV + ((size_t)(b * 256 + chalf * 128)) * NSEQ;

    // Q fragments (B-operand): col i = l31, k = hh*8+e (+16*kc)
    h8 qf[4];
    {
        const _Float16* pq = gT + ((size_t)(b * NSEQ + i0 + l31) * 64 + hh * 8);
#pragma unroll
        for (int kc = 0; kc < 4; ++kc) qf[kc] = *(const h8*)(pq + kc * 16);
    }

    fx16 acc[4];
#pragma unroll
    for (int ct = 0; ct < 4; ++ct)
#pragma unroll
        for (int r = 0; r < 16; ++r) acc[ct][r] = 0.f;

    float m_run = -1e30f, l_run = 0.f;
    int rxv = (l31 & 7) << 4;

    auto STAGE = [&](int buf, int j0s) {
        char* kb = smem + buf * 8192 + wv * 2048;
        char* vb = smem + 16384 + buf * 16384 + wv * 4096;
#pragma unroll
        for (int t = 0; t < 2; ++t) {
            int idx = t * 64 + lane;
            int r = wv * 16 + (idx >> 3);
            int s = idx & 7;
            gll16(fTb + (size_t)(j0s + r) * 64 + ((s ^ (r & 7)) << 3), kb + t * 1024);
        }
#pragma unroll
        for (int t = 0; t < 4; ++t) {
            int idx = t * 64 + lane;
            int r = wv * 32 + (idx >> 3);
            int s = idx & 7;
            gll16(hVb + (size_t)r * NSEQ + j0s + ((s ^ (r & 7)) << 3), vb + t * 1024);
        }
    };

    union U { fx16 v; f2 p[8]; };

    auto body = [&](int cur, int jn) {
        STAGE(cur ^ 1, jn);

        const char* kbase = smem + cur * 8192;
        const char* vbase = smem + 16384 + cur * 16384;

        // ---- S^T = K.Q (log2-scaled) : col=i=l31, row j=8*(r>>2)+4*hh+(r&3)+32*js
        U u0, u1;
#pragma unroll
        for (int r = 0; r < 16; ++r) { u0.v[r] = 0.f; u1.v[r] = 0.f; }
        {
            const char* krow0 = kbase + l31 * 128;
            __builtin_amdgcn_s_setprio(1);
#pragma unroll
            for (int kc = 0; kc < 4; ++kc) {
                h8 kf = *(const h8*)(krow0 + ((((kc * 2 + hh) << 4)) ^ rxv));
                u0.v = __builtin_amdgcn_mfma_f32_32x32x16_f16(kf, qf[kc], u0.v, 0, 0, 0);
            }
            const char* krow1 = krow0 + 32 * 128;
#pragma unroll
            for (int kc = 0; kc < 4; ++kc) {
                h8 kf = *(const h8*)(krow1 + ((((kc * 2 + hh) << 4)) ^ rxv));
                u1.v = __builtin_amdgcn_mfma_f32_32x32x16_f16(kf, qf[kc], u1.v, 0, 0, 0);
            }
            __builtin_amdgcn_s_setprio(0);
        }

        // ---- online softmax in exp2 domain
        float mx = -1e30f;
#pragma unroll
        for (int h = 0; h < 8; ++h) mx = fmaxf(mx, fmaxf(u0.p[h].x, u0.p[h].y));
#pragma unroll
        for (int h = 0; h < 8; ++h) mx = fmaxf(mx, fmaxf(u1.p[h].x, u1.p[h].y));
        mx = fmaxf(mx, __shfl_xor(mx, 32));

        bool norescale = __all(mx - m_run <= 11.5f);   // defer-max (log2 units)
        float mn = norescale ? m_run : fmaxf(m_run, mx);
        if (!norescale) {
            float sc = __builtin_amdgcn_exp2f(m_run - mn);
            m_run = mn;
            l_run *= sc;
            float osc[16];
#pragma unroll
            for (int r = 0; r < 16; ++r)
                osc[r] = __shfl(sc, (r & 3) + 8 * (r >> 2) + 4 * hh);
#pragma unroll
            for (int ct = 0; ct < 4; ++ct)
#pragma unroll
                for (int r = 0; r < 16; ++r) acc[ct][r] *= osc[r];
        }
        f2 mn2 = {mn, mn};
        f2 sum2 = {0.f, 0.f};
#pragma unroll
        for (int h = 0; h < 8; ++h) {
            f2 d0 = u0.p[h] - mn2, d1 = u1.p[h] - mn2;
            f2 p0, p1;
            p0.x = __builtin_amdgcn_exp2f(d0.x);
            p0.y = __builtin_amdgcn_exp2f(d0.y);
            p1.x = __builtin_amdgcn_exp2f(d1.x);
            p1.y = __builtin_amdgcn_exp2f(d1.y);
            u0.p[h] = p0; u1.p[h] = p1;
            sum2 = sum2 + p0 + p1;
        }
        float sum = sum2.x + sum2.y;
        sum += __shfl_xor(sum, 32);
        l_run += sum;

        // ---- PV: lane half hh needs r-quad 2(jc&1)+hh from BOTH halves.
#pragma unroll
        for (int jc = 0; jc < 4; ++jc) {
            const f2* pp = (jc >> 1) ? u1.p : u0.p;
            const int base = 4 * (jc & 1);
            unsigned w0 = pkrtz(pp[base + 0].x, pp[base + 0].y);
            unsigned w1 = pkrtz(pp[base + 1].x, pp[base + 1].y);
            unsigned w2 = pkrtz(pp[base + 2].x, pp[base + 2].y);
            unsigned w3 = pkrtz(pp[base + 3].x, pp[base + 3].y);
            plswap(w0, w2);
            plswap(w1, w3);
            union { unsigned u[4]; h8 v; } pa;
            pa.u[0] = w0;
            pa.u[1] = w1;
            pa.u[2] = w2;
            pa.u[3] = w3;
            __builtin_amdgcn_s_setprio(1);
#pragma unroll
            for (int ct = 0; ct < 4; ++ct) {
                int row = ct * 32 + l31;
                h8 vf = *(const h8*)(vbase + row * 128 + ((((jc * 2 + hh) << 4)) ^ rxv));
                acc[ct] = __builtin_amdgcn_mfma_f32_32x32x16_f16(pa.v, vf, acc[ct], 0, 0, 0);
            }
            __builtin_amdgcn_s_setprio(0);
        }

        asm volatile("s_waitcnt vmcnt(0)" ::: "memory");
        __syncthreads();
    };

    // prologue: fill buffer 0
    STAGE(0, 0);
    asm volatile("s_waitcnt vmcnt(0)" ::: "memory");
    __syncthreads();

#pragma unroll 1
    for (int it = 0; it < NSEQ / 64; it += 2) {
        body(0, ((it + 1) * 64) & (NSEQ - 1));
        body(1, ((it + 2) * 64) & (NSEQ - 1));
    }

    // ---- epilogue: out[b][c][i] = gamma*acc/l + q
    float glf[16];
#pragma unroll
    for (int r = 0; r < 16; ++r) {
        float lsh = __shfl(l_run, (r & 3) + 8 * (r >> 2) + 4 * hh);
        glf[r] = gamma / lsh;
    }
#pragma unroll
    for (int ct = 0; ct < 4; ++ct) {
        int c = chalf * 128 + ct * 32 + l31;
#pragma unroll
        for (int rq = 0; rq < 4; ++rq) {
            int irow = 8 * rq + 4 * hh;
            size_t off = ((size_t)(b * 256 + c)) * NSEQ + i0 + irow;
            fx4 qv = *(const fx4*)(q + off);
            fx4 o;
#pragma unroll
            for (int e = 0; e < 4; ++e)
                o[e] = fmaf(acc[ct][rq * 4 + e], glf[rq * 4 + e], qv[e]);
            *(fx4*)(out + off) = o;
        }
    }
}

// ---------------- launch ----------------
extern "C" void kernel_launch(void* const* d_in, const int* in_sizes, int n_in,
                              void* d_out, int out_size, void* d_ws, size_t ws_size,
                              hipStream_t stream) {
    (void)in_sizes; (void)n_in; (void)out_size; (void)ws_size;
    const float* q   = (const float*)d_in[0];
    const float* k   = (const float*)d_in[1];
    const float* Wf  = (const float*)d_in[2];
    const float* bf_ = (const float*)d_in[3];
    const float* fs  = (const float*)d_in[4];
    const float* fb  = (const float*)d_in[5];
    const float* fm  = (const float*)d_in[6];
    const float* fv  = (const float*)d_in[7];
    const float* Wg  = (const float*)d_in[8];
    const float* bg_ = (const float*)d_in[9];
    const float* gs  = (const float*)d_in[10];
    const float* gb  = (const float*)d_in[11];
    const float* gm  = (const float*)d_in[12];
    const float* gv  = (const float*)d_in[13];
    const float* Wh  = (const float*)d_in[14];
    const float* bh_ = (const float*)d_in[15];
    const float* hs  = (const float*)d_in[16];
    const float* hb  = (const float*)d_in[17];
    const float* hm  = (const float*)d_in[18];
    const float* hv  = (const float*)d_in[19];
    const float* gamma = (const float*)d_in[20];
    float* out = (float*)d_out;

    char* w = (char*)d_ws;
    _Float16* fT = (_Float16*)w;                               // 4 MB
    _Float16* gT = (_Float16*)(w + (size_t)4 * 1024 * 1024);   // 4 MB
    _Float16* hV = (_Float16*)(w + (size_t)8 * 1024 * 1024);   // 16 MB
    float* WfT = (float*)(w + (size_t)24 * 1024 * 1024);
    float* WgT = WfT + 16384;
    float* WhT = WgT + 8192;
    float* Af = WhT + 32768;
    float* Bf = Af + 64;
    float* Ag = Bf + 64;
    float* Bg = Ag + 64;
    float* Ah = Bg + 64;
    float* Bh = Ah + 256;

    prep_kernel<<<128, 256, 0, stream>>>(Wf, Wg, Wh, bf_, fs, fb, fm, fv,
                                         bg_, gs, gb, gm, gv, bh_, hs, hb, hm, hv,
                                         WfT, WgT, WhT, Af, Bf, Ag, Bg, Ah, Bh);

    dim3 cgrid(NSEQ / 32, NB);
    conv_bn_gelu<256, 64, true, false><<<cgrid, 256, 0, stream>>>(q, WfT, Af, Bf, fT);
    conv_bn_gelu<128, 64, true, true ><<<cgrid, 256, 0, stream>>>(k, WgT, Ag, Bg, gT);
    conv_bn_gelu<128, 256, false, false><<<cgrid, 256, 0, stream>>>(k, WhT, Ah, Bh, hV);

    attn_kernel<<<512, 256, 0, stream>>>(fT, gT, hV, q, gamma, out);
}

// Round 13
// 238.996 us; speedup vs baseline: 5.9587x; 5.9587x over previous
//
#include <hip/hip_runtime.h>
#include <math.h>

#define BN_EPS 1e-5f
#define NSEQ 4096
#define NB 8
#define LOG2E 1.4426950408889634f

typedef _Float16 h8 __attribute__((ext_vector_type(8)));
typedef __fp16 fp16x2 __attribute__((ext_vector_type(2)));
typedef float fx16 __attribute__((ext_vector_type(16)));
typedef float fx4 __attribute__((ext_vector_type(4)));
typedef float f2 __attribute__((ext_vector_type(2)));

static __device__ __forceinline__ unsigned pkrtz(float a, float b) {
    fp16x2 r = __builtin_amdgcn_cvt_pkrtz(a, b);
    return __builtin_bit_cast(unsigned, r);
}
// v_permlane32_swap: x' = [x_lo, y_lo], y' = [x_hi, y_hi]
static __device__ __forceinline__ void plswap(unsigned& x, unsigned& y) {
    asm volatile("v_permlane32_swap_b32 %0, %1" : "+v"(x), "+v"(y));
}

static __device__ __forceinline__ void gll16(const void* g, void* l) {
    __builtin_amdgcn_global_load_lds(
        (const __attribute__((address_space(1))) void*)g,
        (__attribute__((address_space(3))) void*)l, 16, 0, 0);
}

// ---------------- prep: transpose weights, fold BN ----------------
__global__ __launch_bounds__(256) void prep_kernel(
    const float* __restrict__ Wf, const float* __restrict__ Wg, const float* __restrict__ Wh,
    const float* __restrict__ bf_, const float* __restrict__ fs, const float* __restrict__ fb,
    const float* __restrict__ fm, const float* __restrict__ fv,
    const float* __restrict__ bg_, const float* __restrict__ gs, const float* __restrict__ gb,
    const float* __restrict__ gm, const float* __restrict__ gv,
    const float* __restrict__ bh_, const float* __restrict__ hs, const float* __restrict__ hb,
    const float* __restrict__ hm, const float* __restrict__ hv,
    float* __restrict__ WfT, float* __restrict__ WgT, float* __restrict__ WhT,
    float* __restrict__ Af, float* __restrict__ Bf, float* __restrict__ Ag, float* __restrict__ Bg,
    float* __restrict__ Ah, float* __restrict__ Bh)
{
    int idx = blockIdx.x * 256 + threadIdx.x;
    if (idx < 16384) {
        int co = idx & 63, ci = idx >> 6;
        WfT[idx] = Wf[co * 256 + ci];
    }
    if (idx < 8192) {
        int co = idx & 63, ci = idx >> 6;
        WgT[idx] = Wg[co * 128 + ci];
    }
    if (idx < 32768) {
        int co = idx & 255, ci = idx >> 8;
        WhT[idx] = Wh[co * 128 + ci];
    }
    if (idx < 64) {
        float A = fs[idx] / sqrtf(fv[idx] + BN_EPS);
        Af[idx] = A; Bf[idx] = (bf_[idx] - fm[idx]) * A + fb[idx];
    } else if (idx < 128) {
        int c = idx - 64;
        float A = gs[c] / sqrtf(gv[c] + BN_EPS);
        Ag[c] = A; Bg[c] = (bg_[c] - gm[c]) * A + gb[c];
    } else if (idx < 384) {
        int c = idx - 128;
        float A = hs[c] / sqrtf(hv[c] + BN_EPS);
        Ah[c] = A; Bh[c] = (bh_[c] - hm[c]) * A + hb[c];
    }
}

// ---------------- conv(1x1) + BN + exact GELU ----------------
// 256 thr = 32 n-slots x 8 co-groups; grid (NSEQ/32, NB) = 1024 -> 4 blk/CU.
// x-only T14 prefetch (1 float4 held across compute = 4 VGPRs); W staged
// transiently (global->reg->LDS inside the staging window, R10-style).
// R12 lesson: register-buffering the W chunk across compute spills at COUT=256.
template <int CIN, int COUT, bool TRANS, bool SCALE>
__global__ __launch_bounds__(256) void conv_bn_gelu(
    const float* __restrict__ in, const float* __restrict__ WT,
    const float* __restrict__ Avec, const float* __restrict__ Bvec,
    _Float16* __restrict__ out)
{
    constexpr int COG = COUT / 8;
    constexpr int NCH = CIN / 32;
    __shared__ float wl[32 * COUT];
    __shared__ float xl[32 * 40];   // [32 ci][32 n] padded to 40
    int tid = threadIdx.x;
    int ns = tid & 31, g = tid >> 5;
    int b = blockIdx.y;
    int n0 = blockIdx.x * 32;
    const float* inp = in + (size_t)b * CIN * NSEQ + n0;
    int xr = tid >> 3, xc4 = tid & 7;

    union { f2 a2[COG / 2]; float a[COG]; } acc;
#pragma unroll
    for (int c = 0; c < COG / 2; ++c) acc.a2[c] = (f2){0.f, 0.f};

    // prologue: chunk 0's x in regs
    float4 xreg = *(const float4*)(inp + (size_t)xr * NSEQ + xc4 * 4);

#pragma unroll 1
    for (int ch = 0; ch < NCH; ++ch) {
        __syncthreads();   // previous chunk's wl/xl reads complete
        *(float4*)(xl + xr * 40 + xc4 * 4) = xreg;
        const float4* wp = (const float4*)(WT + (size_t)ch * 32 * COUT);
        constexpr int Q4 = (32 * COUT / 4) / 256;
#pragma unroll
        for (int e4 = 0; e4 < Q4; ++e4)
            ((float4*)wl)[e4 * 256 + tid] = wp[e4 * 256 + tid];
        __syncthreads();
        // issue next chunk's x load early: latency hides under compute below
        if (ch + 1 < NCH)
            xreg = *(const float4*)(inp + (size_t)((ch + 1) * 32 + xr) * NSEQ + xc4 * 4);
        // compute from LDS
#pragma unroll
        for (int ci = 0; ci < 32; ++ci) {
            float v = xl[ci * 40 + ns];
            const f2* wr = (const f2*)(wl + ci * COUT + g * COG);
            f2 vv = {v, v};
#pragma unroll
            for (int c = 0; c < COG / 2; ++c)
                acc.a2[c] = vv * wr[c] + acc.a2[c];   // v_pk_fma_f32
        }
    }

    union { _Float16 hx[COG]; uint4 u4[COG / 8]; } ob;
#pragma unroll
    for (int c = 0; c < COG; ++c) {
        int co = g * COG + c;
        float y = fmaf(acc.a[c], Avec[co], Bvec[co]);
        float gel = 0.5f * y * (1.f + erff(y * 0.70710678118654752f));
        if (SCALE) gel *= LOG2E;
        if constexpr (TRANS) {
            ob.hx[c] = (_Float16)gel;
        } else {
            out[((size_t)b * COUT + co) * NSEQ + n0 + ns] = (_Float16)gel;
        }
    }
    if constexpr (TRANS) {
        _Float16* op = out + ((size_t)b * NSEQ + n0 + ns) * 64 + g * COG;
#pragma unroll
        for (int u = 0; u < COG / 8; ++u)
            *((uint4*)op + u) = ob.u4[u];
    }
}

// ---------------- flash attention (R9/R10 proven version, unchanged) ----------------
// fT,gT: [B][N][64] fp16 (gT pre-scaled by log2e) ; hV: [B][256][N] fp16
// grid 512: b=blk&7 (XCD-pinned), ib=(blk>>3)&31, chalf=blk>>8 (128 ch each).
// LDS 48KB: K 8KB x2 + V(128ch) 16KB x2, double-buffered, swizzled source.
__global__ __launch_bounds__(256, 2) void attn_kernel(
    const _Float16* __restrict__ fT, const _Float16* __restrict__ gT,
    const _Float16* __restrict__ hV, const float* __restrict__ q,
    const float* __restrict__ gammap, float* __restrict__ out)
{
    __shared__ __align__(16) char smem[49152];

    int tid = threadIdx.x;
    int lane = tid & 63;
    int wv = tid >> 6;
    int l31 = lane & 31;
    int hh = lane >> 5;
    int b = blockIdx.x & 7;
    int ib = (blockIdx.x >> 3) & 31;
    int chalf = blockIdx.x >> 8;
    int i0 = ib * 128 + wv * 32;

    float gamma = gammap[0];
    const _Float16* fTb = fT + (size_t)b * NSEQ * 64;
    const _Float16* hVb = hV + ((size_t)(b * 256 + chalf * 128)) * NSEQ;

    // Q fragments (B-operand): col i = l31, k = hh*8+e (+16*kc)
    h8 qf[4];
    {
        const _Float16* pq = gT + ((size_t)(b * NSEQ + i0 + l31) * 64 + hh * 8);
#pragma unroll
        for (int kc = 0; kc < 4; ++kc) qf[kc] = *(const h8*)(pq + kc * 16);
    }

    fx16 acc[4];
#pragma unroll
    for (int ct = 0; ct < 4; ++ct)
#pragma unroll
        for (int r = 0; r < 16; ++r) acc[ct][r] = 0.f;

    float m_run = -1e30f, l_run = 0.f;
    int rxv = (l31 & 7) << 4;

    auto STAGE = [&](int buf, int j0s) {
        char* kb = smem + buf * 8192 + wv * 2048;
        char* vb = smem + 16384 + buf * 16384 + wv * 4096;
#pragma unroll
        for (int t = 0; t < 2; ++t) {
            int idx = t * 64 + lane;
            int r = wv * 16 + (idx >> 3);
            int s = idx & 7;
            gll16(fTb + (size_t)(j0s + r) * 64 + ((s ^ (r & 7)) << 3), kb + t * 1024);
        }
#pragma unroll
        for (int t = 0; t < 4; ++t) {
            int idx = t * 64 + lane;
            int r = wv * 32 + (idx >> 3);
            int s = idx & 7;
            gll16(hVb + (size_t)r * NSEQ + j0s + ((s ^ (r & 7)) << 3), vb + t * 1024);
        }
    };

    union U { fx16 v; f2 p[8]; };

    auto body = [&](int cur, int jn) {
        STAGE(cur ^ 1, jn);

        const char* kbase = smem + cur * 8192;
        const char* vbase = smem + 16384 + cur * 16384;

        // ---- S^T = K.Q (log2-scaled) : col=i=l31, row j=8*(r>>2)+4*hh+(r&3)+32*js
        U u0, u1;
#pragma unroll
        for (int r = 0; r < 16; ++r) { u0.v[r] = 0.f; u1.v[r] = 0.f; }
        {
            const char* krow0 = kbase + l31 * 128;
            __builtin_amdgcn_s_setprio(1);
#pragma unroll
            for (int kc = 0; kc < 4; ++kc) {
                h8 kf = *(const h8*)(krow0 + ((((kc * 2 + hh) << 4)) ^ rxv));
                u0.v = __builtin_amdgcn_mfma_f32_32x32x16_f16(kf, qf[kc], u0.v, 0, 0, 0);
            }
            const char* krow1 = krow0 + 32 * 128;
#pragma unroll
            for (int kc = 0; kc < 4; ++kc) {
                h8 kf = *(const h8*)(krow1 + ((((kc * 2 + hh) << 4)) ^ rxv));
                u1.v = __builtin_amdgcn_mfma_f32_32x32x16_f16(kf, qf[kc], u1.v, 0, 0, 0);
            }
            __builtin_amdgcn_s_setprio(0);
        }

        // ---- online softmax in exp2 domain
        float mx = -1e30f;
#pragma unroll
        for (int h = 0; h < 8; ++h) mx = fmaxf(mx, fmaxf(u0.p[h].x, u0.p[h].y));
#pragma unroll
        for (int h = 0; h < 8; ++h) mx = fmaxf(mx, fmaxf(u1.p[h].x, u1.p[h].y));
        mx = fmaxf(mx, __shfl_xor(mx, 32));

        bool norescale = __all(mx - m_run <= 11.5f);   // defer-max (log2 units)
        float mn = norescale ? m_run : fmaxf(m_run, mx);
        if (!norescale) {
            float sc = __builtin_amdgcn_exp2f(m_run - mn);
            m_run = mn;
            l_run *= sc;
            float osc[16];
#pragma unroll
            for (int r = 0; r < 16; ++r)
                osc[r] = __shfl(sc, (r & 3) + 8 * (r >> 2) + 4 * hh);
#pragma unroll
            for (int ct = 0; ct < 4; ++ct)
#pragma unroll
                for (int r = 0; r < 16; ++r) acc[ct][r] *= osc[r];
        }
        f2 mn2 = {mn, mn};
        f2 sum2 = {0.f, 0.f};
#pragma unroll
        for (int h = 0; h < 8; ++h) {
            f2 d0 = u0.p[h] - mn2, d1 = u1.p[h] - mn2;
            f2 p0, p1;
            p0.x = __builtin_amdgcn_exp2f(d0.x);
            p0.y = __builtin_amdgcn_exp2f(d0.y);
            p1.x = __builtin_amdgcn_exp2f(d1.x);
            p1.y = __builtin_amdgcn_exp2f(d1.y);
            u0.p[h] = p0; u1.p[h] = p1;
            sum2 = sum2 + p0 + p1;
        }
        float sum = sum2.x + sum2.y;
        sum += __shfl_xor(sum, 32);
        l_run += sum;

        // ---- PV: lane half hh needs r-quad 2(jc&1)+hh from BOTH halves.
#pragma unroll
        for (int jc = 0; jc < 4; ++jc) {
            const f2* pp = (jc >> 1) ? u1.p : u0.p;
            const int base = 4 * (jc & 1);
            unsigned w0 = pkrtz(pp[base + 0].x, pp[base + 0].y);
            unsigned w1 = pkrtz(pp[base + 1].x, pp[base + 1].y);
            unsigned w2 = pkrtz(pp[base + 2].x, pp[base + 2].y);
            unsigned w3 = pkrtz(pp[base + 3].x, pp[base + 3].y);
            plswap(w0, w2);
            plswap(w1, w3);
            union { unsigned u[4]; h8 v; } pa;
            pa.u[0] = w0;
            pa.u[1] = w1;
            pa.u[2] = w2;
            pa.u[3] = w3;
            __builtin_amdgcn_s_setprio(1);
#pragma unroll
            for (int ct = 0; ct < 4; ++ct) {
                int row = ct * 32 + l31;
                h8 vf = *(const h8*)(vbase + row * 128 + ((((jc * 2 + hh) << 4)) ^ rxv));
                acc[ct] = __builtin_amdgcn_mfma_f32_32x32x16_f16(pa.v, vf, acc[ct], 0, 0, 0);
            }
            __builtin_amdgcn_s_setprio(0);
        }

        asm volatile("s_waitcnt vmcnt(0)" ::: "memory");
        __syncthreads();
    };

    // prologue: fill buffer 0
    STAGE(0, 0);
    asm volatile("s_waitcnt vmcnt(0)" ::: "memory");
    __syncthreads();

#pragma unroll 1
    for (int it = 0; it < NSEQ / 64; it += 2) {
        body(0, ((it + 1) * 64) & (NSEQ - 1));
        body(1, ((it + 2) * 64) & (NSEQ - 1));
    }

    // ---- epilogue: out[b][c][i] = gamma*acc/l + q
    float glf[16];
#pragma unroll
    for (int r = 0; r < 16; ++r) {
        float lsh = __shfl(l_run, (r & 3) + 8 * (r >> 2) + 4 * hh);
        glf[r] = gamma / lsh;
    }
#pragma unroll
    for (int ct = 0; ct < 4; ++ct) {
        int c = chalf * 128 + ct * 32 + l31;
#pragma unroll
        for (int rq = 0; rq < 4; ++rq) {
            int irow = 8 * rq + 4 * hh;
            size_t off = ((size_t)(b * 256 + c)) * NSEQ + i0 + irow;
            fx4 qv = *(const fx4*)(q + off);
            fx4 o;
#pragma unroll
            for (int e = 0; e < 4; ++e)
                o[e] = fmaf(acc[ct][rq * 4 + e], glf[rq * 4 + e], qv[e]);
            *(fx4*)(out + off) = o;
        }
    }
}

// ---------------- launch ----------------
extern "C" void kernel_launch(void* const* d_in, const int* in_sizes, int n_in,
                              void* d_out, int out_size, void* d_ws, size_t ws_size,
                              hipStream_t stream) {
    (void)in_sizes; (void)n_in; (void)out_size; (void)ws_size;
    const float* q   = (const float*)d_in[0];
    const float* k   = (const float*)d_in[1];
    const float* Wf  = (const float*)d_in[2];
    const float* bf_ = (const float*)d_in[3];
    const float* fs  = (const float*)d_in[4];
    const float* fb  = (const float*)d_in[5];
    const float* fm  = (const float*)d_in[6];
    const float* fv  = (const float*)d_in[7];
    const float* Wg  = (const float*)d_in[8];
    const float* bg_ = (const float*)d_in[9];
    const float* gs  = (const float*)d_in[10];
    const float* gb  = (const float*)d_in[11];
    const float* gm  = (const float*)d_in[12];
    const float* gv  = (const float*)d_in[13];
    const float* Wh  = (const float*)d_in[14];
    const float* bh_ = (const float*)d_in[15];
    const float* hs  = (const float*)d_in[16];
    const float* hb  = (const float*)d_in[17];
    const float* hm  = (const float*)d_in[18];
    const float* hv  = (const float*)d_in[19];
    const float* gamma = (const float*)d_in[20];
    float* out = (float*)d_out;

    char* w = (char*)d_ws;
    _Float16* fT = (_Float16*)w;                               // 4 MB
    _Float16* gT = (_Float16*)(w + (size_t)4 * 1024 * 1024);   // 4 MB
    _Float16* hV = (_Float16*)(w + (size_t)8 * 1024 * 1024);   // 16 MB
    float* WfT = (float*)(w + (size_t)24 * 1024 * 1024);
    float* WgT = WfT + 16384;
    float* WhT = WgT + 8192;
    float* Af = WhT + 32768;
    float* Bf = Af + 64;
    float* Ag = Bf + 64;
    float* Bg = Ag + 64;
    float* Ah = Bg + 64;
    float* Bh = Ah + 256;

    prep_kernel<<<128, 256, 0, stream>>>(Wf, Wg, Wh, bf_, fs, fb, fm, fv,
                                         bg_, gs, gb, gm, gv, bh_, hs, hb, hm, hv,
                                         WfT, WgT, WhT, Af, Bf, Ag, Bg, Ah, Bh);

    dim3 cgrid(NSEQ / 32, NB);
    conv_bn_gelu<256, 64, true, false><<<cgrid, 256, 0, stream>>>(q, WfT, Af, Bf, fT);
    conv_bn_gelu<128, 64, true, true ><<<cgrid, 256, 0, stream>>>(k, WgT, Ag, Bg, gT);
    conv_bn_gelu<128, 256, false, false><<<cgrid, 256, 0, stream>>>(k, WhT, Ah, Bh, hV);

    attn_kernel<<<512, 256, 0, stream>>>(fT, gT, hV, q, gamma, out);
}

// Round 14
// 231.858 us; speedup vs baseline: 6.1421x; 1.0308x over previous
//
#include <hip/hip_runtime.h>
#include <math.h>

#define BN_EPS 1e-5f
#define NSEQ 4096
#define NB 8
#define LOG2E 1.4426950408889634f

typedef _Float16 h8 __attribute__((ext_vector_type(8)));
typedef __fp16 fp16x2 __attribute__((ext_vector_type(2)));
typedef float fx16 __attribute__((ext_vector_type(16)));
typedef float fx4 __attribute__((ext_vector_type(4)));
typedef float f2 __attribute__((ext_vector_type(2)));

static __device__ __forceinline__ unsigned pkrtz(float a, float b) {
    fp16x2 r = __builtin_amdgcn_cvt_pkrtz(a, b);
    return __builtin_bit_cast(unsigned, r);
}
// v_permlane32_swap: x' = [x_lo, y_lo], y' = [x_hi, y_hi]
static __device__ __forceinline__ void plswap(unsigned& x, unsigned& y) {
    asm volatile("v_permlane32_swap_b32 %0, %1" : "+v"(x), "+v"(y));
}

static __device__ __forceinline__ void gll16(const void* g, void* l) {
    __builtin_amdgcn_global_load_lds(
        (const __attribute__((address_space(1))) void*)g,
        (__attribute__((address_space(3))) void*)l, 16, 0, 0);
}

// ---------------- prep: transpose weights, fold BN ----------------
__global__ __launch_bounds__(256) void prep_kernel(
    const float* __restrict__ Wf, const float* __restrict__ Wg, const float* __restrict__ Wh,
    const float* __restrict__ bf_, const float* __restrict__ fs, const float* __restrict__ fb,
    const float* __restrict__ fm, const float* __restrict__ fv,
    const float* __restrict__ bg_, const float* __restrict__ gs, const float* __restrict__ gb,
    const float* __restrict__ gm, const float* __restrict__ gv,
    const float* __restrict__ bh_, const float* __restrict__ hs, const float* __restrict__ hb,
    const float* __restrict__ hm, const float* __restrict__ hv,
    float* __restrict__ WfT, float* __restrict__ WgT, float* __restrict__ WhT,
    float* __restrict__ Af, float* __restrict__ Bf, float* __restrict__ Ag, float* __restrict__ Bg,
    float* __restrict__ Ah, float* __restrict__ Bh)
{
    int idx = blockIdx.x * 256 + threadIdx.x;
    if (idx < 16384) {
        int co = idx & 63, ci = idx >> 6;
        WfT[idx] = Wf[co * 256 + ci];
    }
    if (idx < 8192) {
        int co = idx & 63, ci = idx >> 6;
        WgT[idx] = Wg[co * 128 + ci];
    }
    if (idx < 32768) {
        int co = idx & 255, ci = idx >> 8;
        WhT[idx] = Wh[co * 128 + ci];
    }
    if (idx < 64) {
        float A = fs[idx] / sqrtf(fv[idx] + BN_EPS);
        Af[idx] = A; Bf[idx] = (bf_[idx] - fm[idx]) * A + fb[idx];
    } else if (idx < 128) {
        int c = idx - 64;
        float A = gs[c] / sqrtf(gv[c] + BN_EPS);
        Ag[c] = A; Bg[c] = (bg_[c] - gm[c]) * A + gb[c];
    } else if (idx < 384) {
        int c = idx - 128;
        float A = hs[c] / sqrtf(hv[c] + BN_EPS);
        Ah[c] = A; Bh[c] = (bh_[c] - hm[c]) * A + hb[c];
    }
}

// ---------------- conv(1x1) + BN + exact GELU body (R13, passing) ----------------
// 256 thr = 32 n-slots x 8 co-groups. x-only T14 prefetch; W staged transiently.
template <int CIN, int COUT, bool TRANS, bool SCALE>
static __device__ __forceinline__ void conv_body(
    const float* __restrict__ in, const float* __restrict__ WT,
    const float* __restrict__ Avec, const float* __restrict__ Bvec,
    _Float16* __restrict__ out, float* wl, float* xl)
{
    constexpr int COG = COUT / 8;
    constexpr int NCH = CIN / 32;
    int tid = threadIdx.x;
    int ns = tid & 31, g = tid >> 5;
    int b = blockIdx.y;
    int n0 = blockIdx.x * 32;
    const float* inp = in + (size_t)b * CIN * NSEQ + n0;
    int xr = tid >> 3, xc4 = tid & 7;

    union { f2 a2[COG / 2]; float a[COG]; } acc;
#pragma unroll
    for (int c = 0; c < COG / 2; ++c) acc.a2[c] = (f2){0.f, 0.f};

    float4 xreg = *(const float4*)(inp + (size_t)xr * NSEQ + xc4 * 4);

#pragma unroll 1
    for (int ch = 0; ch < NCH; ++ch) {
        __syncthreads();   // previous chunk's wl/xl reads complete
        *(float4*)(xl + xr * 40 + xc4 * 4) = xreg;
        const float4* wp = (const float4*)(WT + (size_t)ch * 32 * COUT);
        constexpr int Q4 = (32 * COUT / 4) / 256;
#pragma unroll
        for (int e4 = 0; e4 < Q4; ++e4)
            ((float4*)wl)[e4 * 256 + tid] = wp[e4 * 256 + tid];
        __syncthreads();
        if (ch + 1 < NCH)
            xreg = *(const float4*)(inp + (size_t)((ch + 1) * 32 + xr) * NSEQ + xc4 * 4);
#pragma unroll
        for (int ci = 0; ci < 32; ++ci) {
            float v = xl[ci * 40 + ns];
            const f2* wr = (const f2*)(wl + ci * COUT + g * COG);
            f2 vv = {v, v};
#pragma unroll
            for (int c = 0; c < COG / 2; ++c)
                acc.a2[c] = vv * wr[c] + acc.a2[c];   // v_pk_fma_f32
        }
    }

    union { _Float16 hx[COG]; uint4 u4[COG / 8]; } ob;
#pragma unroll
    for (int c = 0; c < COG; ++c) {
        int co = g * COG + c;
        float y = fmaf(acc.a[c], Avec[co], Bvec[co]);
        float gel = 0.5f * y * (1.f + erff(y * 0.70710678118654752f));
        if (SCALE) gel *= LOG2E;
        if constexpr (TRANS) {
            ob.hx[c] = (_Float16)gel;
        } else {
            out[((size_t)b * COUT + co) * NSEQ + n0 + ns] = (_Float16)gel;
        }
    }
    if constexpr (TRANS) {
        _Float16* op = out + ((size_t)b * NSEQ + n0 + ns) * 64 + g * COG;
#pragma unroll
        for (int u = 0; u < COG / 8; ++u)
            *((uint4*)op + u) = ob.u4[u];
    }
}

// One launch, z selects which conv -> all three run concurrently, one drain.
__global__ __launch_bounds__(256) void conv_fused(
    const float* __restrict__ q, const float* __restrict__ k,
    const float* __restrict__ WfT, const float* __restrict__ WgT,
    const float* __restrict__ WhT,
    const float* __restrict__ Af, const float* __restrict__ Bf,
    const float* __restrict__ Ag, const float* __restrict__ Bg,
    const float* __restrict__ Ah, const float* __restrict__ Bh,
    _Float16* __restrict__ fT, _Float16* __restrict__ gT, _Float16* __restrict__ hV)
{
    __shared__ float wl[32 * 256];
    __shared__ float xl[32 * 40];
    int z = blockIdx.z;
    if (z == 0)      conv_body<256, 64, true, false>(q, WfT, Af, Bf, fT, wl, xl);
    else if (z == 1) conv_body<128, 64, true, true >(k, WgT, Ag, Bg, gT, wl, xl);
    else             conv_body<128, 256, false, false>(k, WhT, Ah, Bh, hV, wl, xl);
}

// ---------------- flash attention (R9/R10 proven version, unchanged) ----------------
// fT,gT: [B][N][64] fp16 (gT pre-scaled by log2e) ; hV: [B][256][N] fp16
// grid 512: b=blk&7 (XCD-pinned), ib=(blk>>3)&31, chalf=blk>>8 (128 ch each).
// LDS 48KB: K 8KB x2 + V(128ch) 16KB x2, double-buffered, swizzled source.
__global__ __launch_bounds__(256, 2) void attn_kernel(
    const _Float16* __restrict__ fT, const _Float16* __restrict__ gT,
    const _Float16* __restrict__ hV, const float* __restrict__ q,
    const float* __restrict__ gammap, float* __restrict__ out)
{
    __shared__ __align__(16) char smem[49152];

    int tid = threadIdx.x;
    int lane = tid & 63;
    int wv = tid >> 6;
    int l31 = lane & 31;
    int hh = lane >> 5;
    int b = blockIdx.x & 7;
    int ib = (blockIdx.x >> 3) & 31;
    int chalf = blockIdx.x >> 8;
    int i0 = ib * 128 + wv * 32;

    float gamma = gammap[0];
    const _Float16* fTb = fT + (size_t)b * NSEQ * 64;
    const _Float16* hVb = hV + ((size_t)(b * 256 + chalf * 128)) * NSEQ;

    // Q fragments (B-operand): col i = l31, k = hh*8+e (+16*kc)
    h8 qf[4];
    {
        const _Float16* pq = gT + ((size_t)(b * NSEQ + i0 + l31) * 64 + hh * 8);
#pragma unroll
        for (int kc = 0; kc < 4; ++kc) qf[kc] = *(const h8*)(pq + kc * 16);
    }

    fx16 acc[4];
#pragma unroll
    for (int ct = 0; ct < 4; ++ct)
#pragma unroll
        for (int r = 0; r < 16; ++r) acc[ct][r] = 0.f;

    float m_run = -1e30f, l_run = 0.f;
    int rxv = (l31 & 7) << 4;

    auto STAGE = [&](int buf, int j0s) {
        char* kb = smem + buf * 8192 + wv * 2048;
        char* vb = smem + 16384 + buf * 16384 + wv * 4096;
#pragma unroll
        for (int t = 0; t < 2; ++t) {
            int idx = t * 64 + lane;
            int r = wv * 16 + (idx >> 3);
            int s = idx & 7;
            gll16(fTb + (size_t)(j0s + r) * 64 + ((s ^ (r & 7)) << 3), kb + t * 1024);
        }
#pragma unroll
        for (int t = 0; t < 4; ++t) {
            int idx = t * 64 + lane;
            int r = wv * 32 + (idx >> 3);
            int s = idx & 7;
            gll16(hVb + (size_t)r * NSEQ + j0s + ((s ^ (r & 7)) << 3), vb + t * 1024);
        }
    };

    union U { fx16 v; f2 p[8]; };

    auto body = [&](int cur, int jn) {
        STAGE(cur ^ 1, jn);

        const char* kbase = smem + cur * 8192;
        const char* vbase = smem + 16384 + cur * 16384;

        // ---- S^T = K.Q (log2-scaled) : col=i=l31, row j=8*(r>>2)+4*hh+(r&3)+32*js
        U u0, u1;
#pragma unroll
        for (int r = 0; r < 16; ++r) { u0.v[r] = 0.f; u1.v[r] = 0.f; }
        {
            const char* krow0 = kbase + l31 * 128;
            __builtin_amdgcn_s_setprio(1);
#pragma unroll
            for (int kc = 0; kc < 4; ++kc) {
                h8 kf = *(const h8*)(krow0 + ((((kc * 2 + hh) << 4)) ^ rxv));
                u0.v = __builtin_amdgcn_mfma_f32_32x32x16_f16(kf, qf[kc], u0.v, 0, 0, 0);
            }
            const char* krow1 = krow0 + 32 * 128;
#pragma unroll
            for (int kc = 0; kc < 4; ++kc) {
                h8 kf = *(const h8*)(krow1 + ((((kc * 2 + hh) << 4)) ^ rxv));
                u1.v = __builtin_amdgcn_mfma_f32_32x32x16_f16(kf, qf[kc], u1.v, 0, 0, 0);
            }
            __builtin_amdgcn_s_setprio(0);
        }

        // ---- online softmax in exp2 domain
        float mx = -1e30f;
#pragma unroll
        for (int h = 0; h < 8; ++h) mx = fmaxf(mx, fmaxf(u0.p[h].x, u0.p[h].y));
#pragma unroll
        for (int h = 0; h < 8; ++h) mx = fmaxf(mx, fmaxf(u1.p[h].x, u1.p[h].y));
        mx = fmaxf(mx, __shfl_xor(mx, 32));

        bool norescale = __all(mx - m_run <= 11.5f);   // defer-max (log2 units)
        float mn = norescale ? m_run : fmaxf(m_run, mx);
        if (!norescale) {
            float sc = __builtin_amdgcn_exp2f(m_run - mn);
            m_run = mn;
            l_run *= sc;
            float osc[16];
#pragma unroll
            for (int r = 0; r < 16; ++r)
                osc[r] = __shfl(sc, (r & 3) + 8 * (r >> 2) + 4 * hh);
#pragma unroll
            for (int ct = 0; ct < 4; ++ct)
#pragma unroll
                for (int r = 0; r < 16; ++r) acc[ct][r] *= osc[r];
        }
        f2 mn2 = {mn, mn};
        f2 sum2 = {0.f, 0.f};
#pragma unroll
        for (int h = 0; h < 8; ++h) {
            f2 d0 = u0.p[h] - mn2, d1 = u1.p[h] - mn2;
            f2 p0, p1;
            p0.x = __builtin_amdgcn_exp2f(d0.x);
            p0.y = __builtin_amdgcn_exp2f(d0.y);
            p1.x = __builtin_amdgcn_exp2f(d1.x);
            p1.y = __builtin_amdgcn_exp2f(d1.y);
            u0.p[h] = p0; u1.p[h] = p1;
            sum2 = sum2 + p0 + p1;
        }
        float sum = sum2.x + sum2.y;
        sum += __shfl_xor(sum, 32);
        l_run += sum;

        // ---- PV: lane half hh needs r-quad 2(jc&1)+hh from BOTH halves.
#pragma unroll
        for (int jc = 0; jc < 4; ++jc) {
            const f2* pp = (jc >> 1) ? u1.p : u0.p;
            const int base = 4 * (jc & 1);
            unsigned w0 = pkrtz(pp[base + 0].x, pp[base + 0].y);
            unsigned w1 = pkrtz(pp[base + 1].x, pp[base + 1].y);
            unsigned w2 = pkrtz(pp[base + 2].x, pp[base + 2].y);
            unsigned w3 = pkrtz(pp[base + 3].x, pp[base + 3].y);
            plswap(w0, w2);
            plswap(w1, w3);
            union { unsigned u[4]; h8 v; } pa;
            pa.u[0] = w0;
            pa.u[1] = w1;
            pa.u[2] = w2;
            pa.u[3] = w3;
            __builtin_amdgcn_s_setprio(1);
#pragma unroll
            for (int ct = 0; ct < 4; ++ct) {
                int row = ct * 32 + l31;
                h8 vf = *(const h8*)(vbase + row * 128 + ((((jc * 2 + hh) << 4)) ^ rxv));
                acc[ct] = __builtin_amdgcn_mfma_f32_32x32x16_f16(pa.v, vf, acc[ct], 0, 0, 0);
            }
            __builtin_amdgcn_s_setprio(0);
        }

        asm volatile("s_waitcnt vmcnt(0)" ::: "memory");
        __syncthreads();
    };

    // prologue: fill buffer 0
    STAGE(0, 0);
    asm volatile("s_waitcnt vmcnt(0)" ::: "memory");
    __syncthreads();

#pragma unroll 1
    for (int it = 0; it < NSEQ / 64; it += 2) {
        body(0, ((it + 1) * 64) & (NSEQ - 1));
        body(1, ((it + 2) * 64) & (NSEQ - 1));
    }

    // ---- epilogue: out[b][c][i] = gamma*acc/l + q
    float glf[16];
#pragma unroll
    for (int r = 0; r < 16; ++r) {
        float lsh = __shfl(l_run, (r & 3) + 8 * (r >> 2) + 4 * hh);
        glf[r] = gamma / lsh;
    }
#pragma unroll
    for (int ct = 0; ct < 4; ++ct) {
        int c = chalf * 128 + ct * 32 + l31;
#pragma unroll
        for (int rq = 0; rq < 4; ++rq) {
            int irow = 8 * rq + 4 * hh;
            size_t off = ((size_t)(b * 256 + c)) * NSEQ + i0 + irow;
            fx4 qv = *(const fx4*)(q + off);
            fx4 o;
#pragma unroll
            for (int e = 0; e < 4; ++e)
                o[e] = fmaf(acc[ct][rq * 4 + e], glf[rq * 4 + e], qv[e]);
            *(fx4*)(out + off) = o;
        }
    }
}

// ---------------- launch ----------------
extern "C" void kernel_launch(void* const* d_in, const int* in_sizes, int n_in,
                              void* d_out, int out_size, void* d_ws, size_t ws_size,
                              hipStream_t stream) {
    (void)in_sizes; (void)n_in; (void)out_size; (void)ws_size;
    const float* q   = (const float*)d_in[0];
    const float* k   = (const float*)d_in[1];
    const float* Wf  = (const float*)d_in[2];
    const float* bf_ = (const float*)d_in[3];
    const float* fs  = (const float*)d_in[4];
    const float* fb  = (const float*)d_in[5];
    const float* fm  = (const float*)d_in[6];
    const float* fv  = (const float*)d_in[7];
    const float* Wg  = (const float*)d_in[8];
    const float* bg_ = (const float*)d_in[9];
    const float* gs  = (const float*)d_in[10];
    const float* gb  = (const float*)d_in[11];
    const float* gm  = (const float*)d_in[12];
    const float* gv  = (const float*)d_in[13];
    const float* Wh  = (const float*)d_in[14];
    const float* bh_ = (const float*)d_in[15];
    const float* hs  = (const float*)d_in[16];
    const float* hb  = (const float*)d_in[17];
    const float* hm  = (const float*)d_in[18];
    const float* hv  = (const float*)d_in[19];
    const float* gamma = (const float*)d_in[20];
    float* out = (float*)d_out;

    char* w = (char*)d_ws;
    _Float16* fT = (_Float16*)w;                               // 4 MB
    _Float16* gT = (_Float16*)(w + (size_t)4 * 1024 * 1024);   // 4 MB
    _Float16* hV = (_Float16*)(w + (size_t)8 * 1024 * 1024);   // 16 MB
    float* WfT = (float*)(w + (size_t)24 * 1024 * 1024);
    float* WgT = WfT + 16384;
    float* WhT = WgT + 8192;
    float* Af = WhT + 32768;
    float* Bf = Af + 64;
    float* Ag = Bf + 64;
    float* Bg = Ag + 64;
    float* Ah = Bg + 64;
    float* Bh = Ah + 256;

    prep_kernel<<<128, 256, 0, stream>>>(Wf, Wg, Wh, bf_, fs, fb, fm, fv,
                                         bg_, gs, gb, gm, gv, bh_, hs, hb, hm, hv,
                                         WfT, WgT, WhT, Af, Bf, Ag, Bg, Ah, Bh);

    dim3 cgrid(NSEQ / 32, NB, 3);
    conv_fused<<<cgrid, 256, 0, stream>>>(q, k, WfT, WgT, WhT,
                                          Af, Bf, Ag, Bg, Ah, Bh, fT, gT, hV);

    attn_kernel<<<512, 256, 0, stream>>>(fT, gT, hV, q, gamma, out);
}

// Round 15
// 184.901 us; speedup vs baseline: 7.7019x; 1.2540x over previous
//
#include <hip/hip_runtime.h>
#include <math.h>

#define BN_EPS 1e-5f
#define NSEQ 4096
#define NB 8
#define LOG2E 1.4426950408889634f

typedef _Float16 h8 __attribute__((ext_vector_type(8)));
typedef __fp16 fp16x2 __attribute__((ext_vector_type(2)));
typedef float fx16 __attribute__((ext_vector_type(16)));
typedef float fx4 __attribute__((ext_vector_type(4)));
typedef float f2 __attribute__((ext_vector_type(2)));

static __device__ __forceinline__ unsigned pkrtz(float a, float b) {
    fp16x2 r = __builtin_amdgcn_cvt_pkrtz(a, b);
    return __builtin_bit_cast(unsigned, r);
}
// v_permlane32_swap: x' = [x_lo, y_lo], y' = [x_hi, y_hi]
static __device__ __forceinline__ void plswap(unsigned& x, unsigned& y) {
    asm volatile("v_permlane32_swap_b32 %0, %1" : "+v"(x), "+v"(y));
}

static __device__ __forceinline__ void gll16(const void* g, void* l) {
    __builtin_amdgcn_global_load_lds(
        (const __attribute__((address_space(1))) void*)g,
        (__attribute__((address_space(3))) void*)l, 16, 0, 0);
}

static __device__ __forceinline__ float gelu_f(float y) {
    return 0.5f * y * (1.f + erff(y * 0.70710678118654752f));
}

// ---------------- prep: convert weights to fp16, fold BN ----------------
__global__ __launch_bounds__(256) void prep_kernel(
    const float* __restrict__ Wf, const float* __restrict__ Wg, const float* __restrict__ Wh,
    const float* __restrict__ bf_, const float* __restrict__ fs, const float* __restrict__ fb,
    const float* __restrict__ fm, const float* __restrict__ fv,
    const float* __restrict__ bg_, const float* __restrict__ gs, const float* __restrict__ gb,
    const float* __restrict__ gm, const float* __restrict__ gv,
    const float* __restrict__ bh_, const float* __restrict__ hs, const float* __restrict__ hb,
    const float* __restrict__ hm, const float* __restrict__ hv,
    _Float16* __restrict__ Wfh, _Float16* __restrict__ Wgh, _Float16* __restrict__ Whh,
    float* __restrict__ Af, float* __restrict__ Bf, float* __restrict__ Ag, float* __restrict__ Bg,
    float* __restrict__ Ah, float* __restrict__ Bh)
{
    int idx = blockIdx.x * 256 + threadIdx.x;
    if (idx < 16384) Wfh[idx] = (_Float16)Wf[idx];   // [co][ci] row-major
    if (idx < 8192)  Wgh[idx] = (_Float16)Wg[idx];
    if (idx < 32768) Whh[idx] = (_Float16)Wh[idx];
    if (idx < 64) {
        float A = fs[idx] / sqrtf(fv[idx] + BN_EPS);
        Af[idx] = A; Bf[idx] = (bf_[idx] - fm[idx]) * A + fb[idx];
    } else if (idx < 128) {
        int c = idx - 64;
        float A = gs[c] / sqrtf(gv[c] + BN_EPS);
        Ag[c] = A; Bg[c] = (bg_[c] - gm[c]) * A + gb[c];
    } else if (idx < 384) {
        int c = idx - 128;
        float A = hs[c] / sqrtf(hv[c] + BN_EPS);
        Ah[c] = A; Bh[c] = (bh_[c] - hm[c]) * A + hb[c];
    }
}

// ---------------- conv(1x1)+BN+GELU via MFMA ----------------
// out[co][n] = GELU(BN(sum_ci W[co][ci] x[ci][n])), fp16 MFMA, f32 accum.
// Block: 64 n-cols x COUT. LDS per K-chunk(32ci): W-chunk [COUT][40 fp16]
// (80B rows) + xT [64n][64B] fp16 (16B-slot XOR by n&3).
// A-frag: lane l31 = co-row, k=hh*8+e (attn-K-verified layout).
// B-frag: lane l31 = n-col,  k=hh*8+e (attn-Q-verified layout).
// D: col=l31=n, row=(r&3)+8*(r>>2)+4*hh (attn-verified).
template <int CIN, int COUT, bool TRANS, bool SCALE>
static __device__ __forceinline__ void conv_mfma(
    const float* __restrict__ x, const _Float16* __restrict__ Wh,
    const float* __restrict__ Av, const float* __restrict__ Bv,
    _Float16* __restrict__ out, char* lds)
{
    constexpr int NCH = CIN / 32;
    constexpr int NACC = (COUT == 256) ? 4 : 1;
    char* xt = lds + COUT * 80;
    int tid = threadIdx.x, lane = tid & 63;
    int wv = tid >> 6, l31 = lane & 31, hh = lane >> 5;
    int b = blockIdx.y, n0 = blockIdx.x * 64;
    const float* xb = x + (size_t)b * CIN * NSEQ + n0;

    fx16 acc[NACC];
#pragma unroll
    for (int a = 0; a < NACC; ++a)
#pragma unroll
        for (int r = 0; r < 16; ++r) acc[a][r] = 0.f;

#pragma unroll 1
    for (int ch = 0; ch < NCH; ++ch) {
        __syncthreads();   // previous chunk's LDS reads done
        // stage W chunk: [COUT][32ci] fp16 -> lds rows of 80B
#pragma unroll
        for (int r = 0; r < COUT / 64; ++r) {
            int e = r * 256 + tid;
            int co = e >> 2, sg = e & 3;
            *(uint4*)(lds + co * 80 + sg * 16) =
                *(const uint4*)(Wh + (size_t)co * CIN + ch * 32 + sg * 8);
        }
        // stage xT chunk: x[32ci][64n] f32 -> xT[n][ci] fp16 (slot-XOR n&3)
#pragma unroll
        for (int r = 0; r < 4; ++r) {
            int e = r * 256 + tid;
            int n = e & 63, cp = e >> 6;   // cp = ci-pair 0..15
            float a = xb[(size_t)(ch * 32 + 2 * cp) * NSEQ + n];
            float c = xb[(size_t)(ch * 32 + 2 * cp + 1) * NSEQ + n];
            unsigned pk = pkrtz(a, c);
            *(unsigned*)(xt + n * 64 + (((cp >> 2) ^ (n & 3)) << 4) + (cp & 3) * 4) = pk;
        }
        __syncthreads();
#pragma unroll
        for (int ks = 0; ks < 2; ++ks) {
            int koff = ks * 32 + hh * 16;   // byte offset of k=ks*16+hh*8 in 80B row
            if constexpr (COUT == 64) {
                int cot = wv & 1, nt = wv >> 1;
                h8 af = *(const h8*)(lds + (cot * 32 + l31) * 80 + koff);
                h8 bf = *(const h8*)(xt + (nt * 32 + l31) * 64 +
                                     (((2 * ks + hh) ^ (l31 & 3)) << 4));
                acc[0] = __builtin_amdgcn_mfma_f32_32x32x16_f16(af, bf, acc[0], 0, 0, 0);
            } else {
                h8 a0 = *(const h8*)(lds + (wv * 32 + l31) * 80 + koff);
                h8 a1 = *(const h8*)(lds + (wv * 32 + 128 + l31) * 80 + koff);
                h8 b0 = *(const h8*)(xt + l31 * 64 + (((2 * ks + hh) ^ (l31 & 3)) << 4));
                h8 b1 = *(const h8*)(xt + (32 + l31) * 64 + (((2 * ks + hh) ^ (l31 & 3)) << 4));
                acc[0] = __builtin_amdgcn_mfma_f32_32x32x16_f16(a0, b0, acc[0], 0, 0, 0);
                acc[1] = __builtin_amdgcn_mfma_f32_32x32x16_f16(a0, b1, acc[1], 0, 0, 0);
                acc[2] = __builtin_amdgcn_mfma_f32_32x32x16_f16(a1, b0, acc[2], 0, 0, 0);
                acc[3] = __builtin_amdgcn_mfma_f32_32x32x16_f16(a1, b1, acc[3], 0, 0, 0);
            }
        }
    }

    // ---- epilogue: BN + GELU + store
    if constexpr (COUT == 64) {
        int cot = wv & 1, nt = wv >> 1;
        int n = n0 + nt * 32 + l31;
        _Float16* op = out + ((size_t)b * NSEQ + n) * 64 + cot * 32 + 4 * hh;
#pragma unroll
        for (int rq = 0; rq < 4; ++rq) {
            int cob = cot * 32 + 8 * rq + 4 * hh;
            float yv[4];
#pragma unroll
            for (int j = 0; j < 4; ++j) {
                float y = fmaf(acc[0][rq * 4 + j], Av[cob + j], Bv[cob + j]);
                y = gelu_f(y);
                if (SCALE) y *= LOG2E;
                yv[j] = y;
            }
            uint2 pk;
            pk.x = pkrtz(yv[0], yv[1]);
            pk.y = pkrtz(yv[2], yv[3]);
            *(uint2*)(op + 8 * rq) = pk;
        }
    } else {
#pragma unroll
        for (int a = 0; a < 4; ++a) {
            int cot = a >> 1, nt = a & 1;
            int n = n0 + nt * 32 + l31;
#pragma unroll
            for (int r = 0; r < 16; ++r) {
                int co = wv * 32 + cot * 128 + (r & 3) + 8 * (r >> 2) + 4 * hh;
                float y = fmaf(acc[a][r], Av[co], Bv[co]);
                out[((size_t)b * COUT + co) * NSEQ + n] = (_Float16)gelu_f(y);
            }
        }
    }
}

__global__ __launch_bounds__(256) void conv_fused(
    const float* __restrict__ q, const float* __restrict__ k,
    const _Float16* __restrict__ Wfh, const _Float16* __restrict__ Wgh,
    const _Float16* __restrict__ Whh,
    const float* __restrict__ Af, const float* __restrict__ Bf,
    const float* __restrict__ Ag, const float* __restrict__ Bg,
    const float* __restrict__ Ah, const float* __restrict__ Bh,
    _Float16* __restrict__ fT, _Float16* __restrict__ gT, _Float16* __restrict__ hV)
{
    __shared__ __align__(16) char lds[24576];   // 256*80 + 64*64
    int z = blockIdx.z;
    if (z == 0)      conv_mfma<256, 64, true, false>(q, Wfh, Af, Bf, fT, lds);
    else if (z == 1) conv_mfma<128, 64, true, true >(k, Wgh, Ag, Bg, gT, lds);
    else             conv_mfma<128, 256, false, false>(k, Whh, Ah, Bh, hV, lds);
}

// ---------------- flash attention (R9-R14 proven version, unchanged) ----------------
__global__ __launch_bounds__(256, 2) void attn_kernel(
    const _Float16* __restrict__ fT, const _Float16* __restrict__ gT,
    const _Float16* __restrict__ hV, const float* __restrict__ q,
    const float* __restrict__ gammap, float* __restrict__ out)
{
    __shared__ __align__(16) char smem[49152];

    int tid = threadIdx.x;
    int lane = tid & 63;
    int wv = tid >> 6;
    int l31 = lane & 31;
    int hh = lane >> 5;
    int b = blockIdx.x & 7;
    int ib = (blockIdx.x >> 3) & 31;
    int chalf = blockIdx.x >> 8;
    int i0 = ib * 128 + wv * 32;

    float gamma = gammap[0];
    const _Float16* fTb = fT + (size_t)b * NSEQ * 64;
    const _Float16* hVb = hV + ((size_t)(b * 256 + chalf * 128)) * NSEQ;

    h8 qf[4];
    {
        const _Float16* pq = gT + ((size_t)(b * NSEQ + i0 + l31) * 64 + hh * 8);
#pragma unroll
        for (int kc = 0; kc < 4; ++kc) qf[kc] = *(const h8*)(pq + kc * 16);
    }

    fx16 acc[4];
#pragma unroll
    for (int ct = 0; ct < 4; ++ct)
#pragma unroll
        for (int r = 0; r < 16; ++r) acc[ct][r] = 0.f;

    float m_run = -1e30f, l_run = 0.f;
    int rxv = (l31 & 7) << 4;

    auto STAGE = [&](int buf, int j0s) {
        char* kb = smem + buf * 8192 + wv * 2048;
        char* vb = smem + 16384 + buf * 16384 + wv * 4096;
#pragma unroll
        for (int t = 0; t < 2; ++t) {
            int idx = t * 64 + lane;
            int r = wv * 16 + (idx >> 3);
            int s = idx & 7;
            gll16(fTb + (size_t)(j0s + r) * 64 + ((s ^ (r & 7)) << 3), kb + t * 1024);
        }
#pragma unroll
        for (int t = 0; t < 4; ++t) {
            int idx = t * 64 + lane;
            int r = wv * 32 + (idx >> 3);
            int s = idx & 7;
            gll16(hVb + (size_t)r * NSEQ + j0s + ((s ^ (r & 7)) << 3), vb + t * 1024);
        }
    };

    union U { fx16 v; f2 p[8]; };

    auto body = [&](int cur, int jn) {
        STAGE(cur ^ 1, jn);

        const char* kbase = smem + cur * 8192;
        const char* vbase = smem + 16384 + cur * 16384;

        U u0, u1;
#pragma unroll
        for (int r = 0; r < 16; ++r) { u0.v[r] = 0.f; u1.v[r] = 0.f; }
        {
            const char* krow0 = kbase + l31 * 128;
            __builtin_amdgcn_s_setprio(1);
#pragma unroll
            for (int kc = 0; kc < 4; ++kc) {
                h8 kf = *(const h8*)(krow0 + ((((kc * 2 + hh) << 4)) ^ rxv));
                u0.v = __builtin_amdgcn_mfma_f32_32x32x16_f16(kf, qf[kc], u0.v, 0, 0, 0);
            }
            const char* krow1 = krow0 + 32 * 128;
#pragma unroll
            for (int kc = 0; kc < 4; ++kc) {
                h8 kf = *(const h8*)(krow1 + ((((kc * 2 + hh) << 4)) ^ rxv));
                u1.v = __builtin_amdgcn_mfma_f32_32x32x16_f16(kf, qf[kc], u1.v, 0, 0, 0);
            }
            __builtin_amdgcn_s_setprio(0);
        }

        float mx = -1e30f;
#pragma unroll
        for (int h = 0; h < 8; ++h) mx = fmaxf(mx, fmaxf(u0.p[h].x, u0.p[h].y));
#pragma unroll
        for (int h = 0; h < 8; ++h) mx = fmaxf(mx, fmaxf(u1.p[h].x, u1.p[h].y));
        mx = fmaxf(mx, __shfl_xor(mx, 32));

        bool norescale = __all(mx - m_run <= 11.5f);
        float mn = norescale ? m_run : fmaxf(m_run, mx);
        if (!norescale) {
            float sc = __builtin_amdgcn_exp2f(m_run - mn);
            m_run = mn;
            l_run *= sc;
            float osc[16];
#pragma unroll
            for (int r = 0; r < 16; ++r)
                osc[r] = __shfl(sc, (r & 3) + 8 * (r >> 2) + 4 * hh);
#pragma unroll
            for (int ct = 0; ct < 4; ++ct)
#pragma unroll
                for (int r = 0; r < 16; ++r) acc[ct][r] *= osc[r];
        }
        f2 mn2 = {mn, mn};
        f2 sum2 = {0.f, 0.f};
#pragma unroll
        for (int h = 0; h < 8; ++h) {
            f2 d0 = u0.p[h] - mn2, d1 = u1.p[h] - mn2;
            f2 p0, p1;
            p0.x = __builtin_amdgcn_exp2f(d0.x);
            p0.y = __builtin_amdgcn_exp2f(d0.y);
            p1.x = __builtin_amdgcn_exp2f(d1.x);
            p1.y = __builtin_amdgcn_exp2f(d1.y);
            u0.p[h] = p0; u1.p[h] = p1;
            sum2 = sum2 + p0 + p1;
        }
        float sum = sum2.x + sum2.y;
        sum += __shfl_xor(sum, 32);
        l_run += sum;

#pragma unroll
        for (int jc = 0; jc < 4; ++jc) {
            const f2* pp = (jc >> 1) ? u1.p : u0.p;
            const int base = 4 * (jc & 1);
            unsigned w0 = pkrtz(pp[base + 0].x, pp[base + 0].y);
            unsigned w1 = pkrtz(pp[base + 1].x, pp[base + 1].y);
            unsigned w2 = pkrtz(pp[base + 2].x, pp[base + 2].y);
            unsigned w3 = pkrtz(pp[base + 3].x, pp[base + 3].y);
            plswap(w0, w2);
            plswap(w1, w3);
            union { unsigned u[4]; h8 v; } pa;
            pa.u[0] = w0;
            pa.u[1] = w1;
            pa.u[2] = w2;
            pa.u[3] = w3;
            __builtin_amdgcn_s_setprio(1);
#pragma unroll
            for (int ct = 0; ct < 4; ++ct) {
                int row = ct * 32 + l31;
                h8 vf = *(const h8*)(vbase + row * 128 + ((((jc * 2 + hh) << 4)) ^ rxv));
                acc[ct] = __builtin_amdgcn_mfma_f32_32x32x16_f16(pa.v, vf, acc[ct], 0, 0, 0);
            }
            __builtin_amdgcn_s_setprio(0);
        }

        asm volatile("s_waitcnt vmcnt(0)" ::: "memory");
        __syncthreads();
    };

    STAGE(0, 0);
    asm volatile("s_waitcnt vmcnt(0)" ::: "memory");
    __syncthreads();

#pragma unroll 1
    for (int it = 0; it < NSEQ / 64; it += 2) {
        body(0, ((it + 1) * 64) & (NSEQ - 1));
        body(1, ((it + 2) * 64) & (NSEQ - 1));
    }

    float glf[16];
#pragma unroll
    for (int r = 0; r < 16; ++r) {
        float lsh = __shfl(l_run, (r & 3) + 8 * (r >> 2) + 4 * hh);
        glf[r] = gamma / lsh;
    }
#pragma unroll
    for (int ct = 0; ct < 4; ++ct) {
        int c = chalf * 128 + ct * 32 + l31;
#pragma unroll
        for (int rq = 0; rq < 4; ++rq) {
            int irow = 8 * rq + 4 * hh;
            size_t off = ((size_t)(b * 256 + c)) * NSEQ + i0 + irow;
            fx4 qv = *(const fx4*)(q + off);
            fx4 o;
#pragma unroll
            for (int e = 0; e < 4; ++e)
                o[e] = fmaf(acc[ct][rq * 4 + e], glf[rq * 4 + e], qv[e]);
            *(fx4*)(out + off) = o;
        }
    }
}

// ---------------- launch ----------------
extern "C" void kernel_launch(void* const* d_in, const int* in_sizes, int n_in,
                              void* d_out, int out_size, void* d_ws, size_t ws_size,
                              hipStream_t stream) {
    (void)in_sizes; (void)n_in; (void)out_size; (void)ws_size;
    const float* q   = (const float*)d_in[0];
    const float* k   = (const float*)d_in[1];
    const float* Wf  = (const float*)d_in[2];
    const float* bf_ = (const float*)d_in[3];
    const float* fs  = (const float*)d_in[4];
    const float* fb  = (const float*)d_in[5];
    const float* fm  = (const float*)d_in[6];
    const float* fv  = (const float*)d_in[7];
    const float* Wg  = (const float*)d_in[8];
    const float* bg_ = (const float*)d_in[9];
    const float* gs  = (const float*)d_in[10];
    const float* gb  = (const float*)d_in[11];
    const float* gm  = (const float*)d_in[12];
    const float* gv  = (const float*)d_in[13];
    const float* Wh  = (const float*)d_in[14];
    const float* bh_ = (const float*)d_in[15];
    const float* hs  = (const float*)d_in[16];
    const float* hb  = (const float*)d_in[17];
    const float* hm  = (const float*)d_in[18];
    const float* hv  = (const float*)d_in[19];
    const float* gamma = (const float*)d_in[20];
    float* out = (float*)d_out;

    char* w = (char*)d_ws;
    _Float16* fT = (_Float16*)w;                               // 4 MB
    _Float16* gT = (_Float16*)(w + (size_t)4 * 1024 * 1024);   // 4 MB
    _Float16* hV = (_Float16*)(w + (size_t)8 * 1024 * 1024);   // 16 MB
    _Float16* Wfh = (_Float16*)(w + (size_t)24 * 1024 * 1024); // 32 KB
    _Float16* Wgh = Wfh + 16384;                               // 16 KB
    _Float16* Whh = Wgh + 8192;                                // 64 KB
    float* Af = (float*)(Whh + 32768);
    float* Bf = Af + 64;
    float* Ag = Bf + 64;
    float* Bg = Ag + 64;
    float* Ah = Bg + 64;
    float* Bh = Ah + 256;

    prep_kernel<<<128, 256, 0, stream>>>(Wf, Wg, Wh, bf_, fs, fb, fm, fv,
                                         bg_, gs, gb, gm, gv, bh_, hs, hb, hm, hv,
                                         Wfh, Wgh, Whh, Af, Bf, Ag, Bg, Ah, Bh);

    dim3 cgrid(NSEQ / 64, NB, 3);
    conv_fused<<<cgrid, 256, 0, stream>>>(q, k, Wfh, Wgh, Whh,
                                          Af, Bf, Ag, Bg, Ah, Bh, fT, gT, hV);

    attn_kernel<<<512, 256, 0, stream>>>(fT, gT, hV, q, gamma, out);
}

// Round 17
// 184.782 us; speedup vs baseline: 7.7069x; 1.0006x over previous
//
#include <hip/hip_runtime.h>
#include <math.h>

#define BN_EPS 1e-5f
#define NSEQ 4096
#define NB 8
#define LOG2E 1.4426950408889634f

typedef _Float16 h8 __attribute__((ext_vector_type(8)));
typedef __fp16 fp16x2 __attribute__((ext_vector_type(2)));
typedef float fx16 __attribute__((ext_vector_type(16)));
typedef float fx4 __attribute__((ext_vector_type(4)));
typedef float f2 __attribute__((ext_vector_type(2)));

static __device__ __forceinline__ unsigned pkrtz(float a, float b) {
    fp16x2 r = __builtin_amdgcn_cvt_pkrtz(a, b);
    return __builtin_bit_cast(unsigned, r);
}
// v_permlane32_swap: x' = [x_lo, y_lo], y' = [x_hi, y_hi]
static __device__ __forceinline__ void plswap(unsigned& x, unsigned& y) {
    asm volatile("v_permlane32_swap_b32 %0, %1" : "+v"(x), "+v"(y));
}

static __device__ __forceinline__ void gll16(const void* g, void* l) {
    __builtin_amdgcn_global_load_lds(
        (const __attribute__((address_space(1))) void*)g,
        (__attribute__((address_space(3))) void*)l, 16, 0, 0);
}

static __device__ __forceinline__ float gelu_f(float y) {
    return 0.5f * y * (1.f + erff(y * 0.70710678118654752f));
}

// ---------------- prep: convert weights to fp16, fold BN ----------------
__global__ __launch_bounds__(256) void prep_kernel(
    const float* __restrict__ Wf, const float* __restrict__ Wg, const float* __restrict__ Wh,
    const float* __restrict__ bf_, const float* __restrict__ fs, const float* __restrict__ fb,
    const float* __restrict__ fm, const float* __restrict__ fv,
    const float* __restrict__ bg_, const float* __restrict__ gs, const float* __restrict__ gb,
    const float* __restrict__ gm, const float* __restrict__ gv,
    const float* __restrict__ bh_, const float* __restrict__ hs, const float* __restrict__ hb,
    const float* __restrict__ hm, const float* __restrict__ hv,
    _Float16* __restrict__ Wfh, _Float16* __restrict__ Wgh, _Float16* __restrict__ Whh,
    float* __restrict__ Af, float* __restrict__ Bf, float* __restrict__ Ag, float* __restrict__ Bg,
    float* __restrict__ Ah, float* __restrict__ Bh)
{
    int idx = blockIdx.x * 256 + threadIdx.x;
    if (idx < 16384) Wfh[idx] = (_Float16)Wf[idx];   // [co][ci] row-major
    if (idx < 8192)  Wgh[idx] = (_Float16)Wg[idx];
    if (idx < 32768) Whh[idx] = (_Float16)Wh[idx];
    if (idx < 64) {
        float A = fs[idx] / sqrtf(fv[idx] + BN_EPS);
        Af[idx] = A; Bf[idx] = (bf_[idx] - fm[idx]) * A + fb[idx];
    } else if (idx < 128) {
        int c = idx - 64;
        float A = gs[c] / sqrtf(gv[c] + BN_EPS);
        Ag[c] = A; Bg[c] = (bg_[c] - gm[c]) * A + gb[c];
    } else if (idx < 384) {
        int c = idx - 128;
        float A = hs[c] / sqrtf(hv[c] + BN_EPS);
        Ah[c] = A; Bh[c] = (bh_[c] - hm[c]) * A + hb[c];
    }
}

// ---------------- conv(1x1)+BN+GELU via MFMA (R15, passing) ----------------
template <int CIN, int COUT, bool TRANS, bool SCALE>
static __device__ __forceinline__ void conv_mfma(
    const float* __restrict__ x, const _Float16* __restrict__ Wh,
    const float* __restrict__ Av, const float* __restrict__ Bv,
    _Float16* __restrict__ out, char* lds)
{
    constexpr int NCH = CIN / 32;
    constexpr int NACC = (COUT == 256) ? 4 : 1;
    char* xt = lds + COUT * 80;
    int tid = threadIdx.x, lane = tid & 63;
    int wv = tid >> 6, l31 = lane & 31, hh = lane >> 5;
    int b = blockIdx.y, n0 = blockIdx.x * 64;
    const float* xb = x + (size_t)b * CIN * NSEQ + n0;

    fx16 acc[NACC];
#pragma unroll
    for (int a = 0; a < NACC; ++a)
#pragma unroll
        for (int r = 0; r < 16; ++r) acc[a][r] = 0.f;

#pragma unroll 1
    for (int ch = 0; ch < NCH; ++ch) {
        __syncthreads();
#pragma unroll
        for (int r = 0; r < COUT / 64; ++r) {
            int e = r * 256 + tid;
            int co = e >> 2, sg = e & 3;
            *(uint4*)(lds + co * 80 + sg * 16) =
                *(const uint4*)(Wh + (size_t)co * CIN + ch * 32 + sg * 8);
        }
#pragma unroll
        for (int r = 0; r < 4; ++r) {
            int e = r * 256 + tid;
            int n = e & 63, cp = e >> 6;
            float a = xb[(size_t)(ch * 32 + 2 * cp) * NSEQ + n];
            float c = xb[(size_t)(ch * 32 + 2 * cp + 1) * NSEQ + n];
            unsigned pk = pkrtz(a, c);
            *(unsigned*)(xt + n * 64 + (((cp >> 2) ^ (n & 3)) << 4) + (cp & 3) * 4) = pk;
        }
        __syncthreads();
#pragma unroll
        for (int ks = 0; ks < 2; ++ks) {
            int koff = ks * 32 + hh * 16;
            if constexpr (COUT == 64) {
                int cot = wv & 1, nt = wv >> 1;
                h8 af = *(const h8*)(lds + (cot * 32 + l31) * 80 + koff);
                h8 bf = *(const h8*)(xt + (nt * 32 + l31) * 64 +
                                     (((2 * ks + hh) ^ (l31 & 3)) << 4));
                acc[0] = __builtin_amdgcn_mfma_f32_32x32x16_f16(af, bf, acc[0], 0, 0, 0);
            } else {
                h8 a0 = *(const h8*)(lds + (wv * 32 + l31) * 80 + koff);
                h8 a1 = *(const h8*)(lds + (wv * 32 + 128 + l31) * 80 + koff);
                h8 b0 = *(const h8*)(xt + l31 * 64 + (((2 * ks + hh) ^ (l31 & 3)) << 4));
                h8 b1 = *(const h8*)(xt + (32 + l31) * 64 + (((2 * ks + hh) ^ (l31 & 3)) << 4));
                acc[0] = __builtin_amdgcn_mfma_f32_32x32x16_f16(a0, b0, acc[0], 0, 0, 0);
                acc[1] = __builtin_amdgcn_mfma_f32_32x32x16_f16(a0, b1, acc[1], 0, 0, 0);
                acc[2] = __builtin_amdgcn_mfma_f32_32x32x16_f16(a1, b0, acc[2], 0, 0, 0);
                acc[3] = __builtin_amdgcn_mfma_f32_32x32x16_f16(a1, b1, acc[3], 0, 0, 0);
            }
        }
    }

    if constexpr (COUT == 64) {
        int cot = wv & 1, nt = wv >> 1;
        int n = n0 + nt * 32 + l31;
        _Float16* op = out + ((size_t)b * NSEQ + n) * 64 + cot * 32 + 4 * hh;
#pragma unroll
        for (int rq = 0; rq < 4; ++rq) {
            int cob = cot * 32 + 8 * rq + 4 * hh;
            float yv[4];
#pragma unroll
            for (int j = 0; j < 4; ++j) {
                float y = fmaf(acc[0][rq * 4 + j], Av[cob + j], Bv[cob + j]);
                y = gelu_f(y);
                if (SCALE) y *= LOG2E;
                yv[j] = y;
            }
            uint2 pk;
            pk.x = pkrtz(yv[0], yv[1]);
            pk.y = pkrtz(yv[2], yv[3]);
            *(uint2*)(op + 8 * rq) = pk;
        }
    } else {
#pragma unroll
        for (int a = 0; a < 4; ++a) {
            int cot = a >> 1, nt = a & 1;
            int n = n0 + nt * 32 + l31;
#pragma unroll
            for (int r = 0; r < 16; ++r) {
                int co = wv * 32 + cot * 128 + (r & 3) + 8 * (r >> 2) + 4 * hh;
                float y = fmaf(acc[a][r], Av[co], Bv[co]);
                out[((size_t)b * COUT + co) * NSEQ + n] = (_Float16)gelu_f(y);
            }
        }
    }
}

__global__ __launch_bounds__(256) void conv_fused(
    const float* __restrict__ q, const float* __restrict__ k,
    const _Float16* __restrict__ Wfh, const _Float16* __restrict__ Wgh,
    const _Float16* __restrict__ Whh,
    const float* __restrict__ Af, const float* __restrict__ Bf,
    const float* __restrict__ Ag, const float* __restrict__ Bg,
    const float* __restrict__ Ah, const float* __restrict__ Bh,
    _Float16* __restrict__ fT, _Float16* __restrict__ gT, _Float16* __restrict__ hV)
{
    __shared__ __align__(16) char lds[24576];   // 256*80 + 64*64
    int z = blockIdx.z;
    if (z == 0)      conv_mfma<256, 64, true, false>(q, Wfh, Af, Bf, fT, lds);
    else if (z == 1) conv_mfma<128, 64, true, true >(k, Wgh, Ag, Bg, gT, lds);
    else             conv_mfma<128, 256, false, false>(k, Whh, Ah, Bh, hV, lds);
}

// ---------------- flash attention (R9-R15 proven version, unchanged) ----------------
__global__ __launch_bounds__(256, 2) void attn_kernel(
    const _Float16* __restrict__ fT, const _Float16* __restrict__ gT,
    const _Float16* __restrict__ hV, const float* __restrict__ q,
    const float* __restrict__ gammap, float* __restrict__ out)
{
    __shared__ __align__(16) char smem[49152];

    int tid = threadIdx.x;
    int lane = tid & 63;
    int wv = tid >> 6;
    int l31 = lane & 31;
    int hh = lane >> 5;
    int b = blockIdx.x & 7;
    int ib = (blockIdx.x >> 3) & 31;
    int chalf = blockIdx.x >> 8;
    int i0 = ib * 128 + wv * 32;

    float gamma = gammap[0];
    const _Float16* fTb = fT + (size_t)b * NSEQ * 64;
    const _Float16* hVb = hV + ((size_t)(b * 256 + chalf * 128)) * NSEQ;

    h8 qf[4];
    {
        const _Float16* pq = gT + ((size_t)(b * NSEQ + i0 + l31) * 64 + hh * 8);
#pragma unroll
        for (int kc = 0; kc < 4; ++kc) qf[kc] = *(const h8*)(pq + kc * 16);
    }

    fx16 acc[4];
#pragma unroll
    for (int ct = 0; ct < 4; ++ct)
#pragma unroll
        for (int r = 0; r < 16; ++r) acc[ct][r] = 0.f;

    float m_run = -1e30f, l_run = 0.f;
    int rxv = (l31 & 7) << 4;

    auto STAGE = [&](int buf, int j0s) {
        char* kb = smem + buf * 8192 + wv * 2048;
        char* vb = smem + 16384 + buf * 16384 + wv * 4096;
#pragma unroll
        for (int t = 0; t < 2; ++t) {
            int idx = t * 64 + lane;
            int r = wv * 16 + (idx >> 3);
            int s = idx & 7;
            gll16(fTb + (size_t)(j0s + r) * 64 + ((s ^ (r & 7)) << 3), kb + t * 1024);
        }
#pragma unroll
        for (int t = 0; t < 4; ++t) {
            int idx = t * 64 + lane;
            int r = wv * 32 + (idx >> 3);
            int s = idx & 7;
            gll16(hVb + (size_t)r * NSEQ + j0s + ((s ^ (r & 7)) << 3), vb + t * 1024);
        }
    };

    union U { fx16 v; f2 p[8]; };

    auto body = [&](int cur, int jn) {
        STAGE(cur ^ 1, jn);

        const char* kbase = smem + cur * 8192;
        const char* vbase = smem + 16384 + cur * 16384;

        U u0, u1;
#pragma unroll
        for (int r = 0; r < 16; ++r) { u0.v[r] = 0.f; u1.v[r] = 0.f; }
        {
            const char* krow0 = kbase + l31 * 128;
            __builtin_amdgcn_s_setprio(1);
#pragma unroll
            for (int kc = 0; kc < 4; ++kc) {
                h8 kf = *(const h8*)(krow0 + ((((kc * 2 + hh) << 4)) ^ rxv));
                u0.v = __builtin_amdgcn_mfma_f32_32x32x16_f16(kf, qf[kc], u0.v, 0, 0, 0);
            }
            const char* krow1 = krow0 + 32 * 128;
#pragma unroll
            for (int kc = 0; kc < 4; ++kc) {
                h8 kf = *(const h8*)(krow1 + ((((kc * 2 + hh) << 4)) ^ rxv));
                u1.v = __builtin_amdgcn_mfma_f32_32x32x16_f16(kf, qf[kc], u1.v, 0, 0, 0);
            }
            __builtin_amdgcn_s_setprio(0);
        }

        float mx = -1e30f;
#pragma unroll
        for (int h = 0; h < 8; ++h) mx = fmaxf(mx, fmaxf(u0.p[h].x, u0.p[h].y));
#pragma unroll
        for (int h = 0; h < 8; ++h) mx = fmaxf(mx, fmaxf(u1.p[h].x, u1.p[h].y));
        mx = fmaxf(mx, __shfl_xor(mx, 32));

        bool norescale = __all(mx - m_run <= 11.5f);
        float mn = norescale ? m_run : fmaxf(m_run, mx);
        if (!norescale) {
            float sc = __builtin_amdgcn_exp2f(m_run - mn);
            m_run = mn;
            l_run *= sc;
            float osc[16];
#pragma unroll
            for (int r = 0; r < 16; ++r)
                osc[r] = __shfl(sc, (r & 3) + 8 * (r >> 2) + 4 * hh);
#pragma unroll
            for (int ct = 0; ct < 4; ++ct)
#pragma unroll
                for (int r = 0; r < 16; ++r) acc[ct][r] *= osc[r];
        }
        f2 mn2 = {mn, mn};
        f2 sum2 = {0.f, 0.f};
#pragma unroll
        for (int h = 0; h < 8; ++h) {
            f2 d0 = u0.p[h] - mn2, d1 = u1.p[h] - mn2;
            f2 p0, p1;
            p0.x = __builtin_amdgcn_exp2f(d0.x);
            p0.y = __builtin_amdgcn_exp2f(d0.y);
            p1.x = __builtin_amdgcn_exp2f(d1.x);
            p1.y = __builtin_amdgcn_exp2f(d1.y);
            u0.p[h] = p0; u1.p[h] = p1;
            sum2 = sum2 + p0 + p1;
        }
        float sum = sum2.x + sum2.y;
        sum += __shfl_xor(sum, 32);
        l_run += sum;

#pragma unroll
        for (int jc = 0; jc < 4; ++jc) {
            const f2* pp = (jc >> 1) ? u1.p : u0.p;
            const int base = 4 * (jc & 1);
            unsigned w0 = pkrtz(pp[base + 0].x, pp[base + 0].y);
            unsigned w1 = pkrtz(pp[base + 1].x, pp[base + 1].y);
            unsigned w2 = pkrtz(pp[base + 2].x, pp[base + 2].y);
            unsigned w3 = pkrtz(pp[base + 3].x, pp[base + 3].y);
            plswap(w0, w2);
            plswap(w1, w3);
            union { unsigned u[4]; h8 v; } pa;
            pa.u[0] = w0;
            pa.u[1] = w1;
            pa.u[2] = w2;
            pa.u[3] = w3;
            __builtin_amdgcn_s_setprio(1);
#pragma unroll
            for (int ct = 0; ct < 4; ++ct) {
                int row = ct * 32 + l31;
                h8 vf = *(const h8*)(vbase + row * 128 + ((((jc * 2 + hh) << 4)) ^ rxv));
                acc[ct] = __builtin_amdgcn_mfma_f32_32x32x16_f16(pa.v, vf, acc[ct], 0, 0, 0);
            }
            __builtin_amdgcn_s_setprio(0);
        }

        asm volatile("s_waitcnt vmcnt(0)" ::: "memory");
        __syncthreads();
    };

    STAGE(0, 0);
    asm volatile("s_waitcnt vmcnt(0)" ::: "memory");
    __syncthreads();

#pragma unroll 1
    for (int it = 0; it < NSEQ / 64; it += 2) {
        body(0, ((it + 1) * 64) & (NSEQ - 1));
        body(1, ((it + 2) * 64) & (NSEQ - 1));
    }

    float glf[16];
#pragma unroll
    for (int r = 0; r < 16; ++r) {
        float lsh = __shfl(l_run, (r & 3) + 8 * (r >> 2) + 4 * hh);
        glf[r] = gamma / lsh;
    }
#pragma unroll
    for (int ct = 0; ct < 4; ++ct) {
        int c = chalf * 128 + ct * 32 + l31;
#pragma unroll
        for (int rq = 0; rq < 4; ++rq) {
            int irow = 8 * rq + 4 * hh;
            size_t off = ((size_t)(b * 256 + c)) * NSEQ + i0 + irow;
            fx4 qv = *(const fx4*)(q + off);
            fx4 o;
#pragma unroll
            for (int e = 0; e < 4; ++e)
                o[e] = fmaf(acc[ct][rq * 4 + e], glf[rq * 4 + e], qv[e]);
            *(fx4*)(out + off) = o;
        }
    }
}

// ---------------- launch ----------------
extern "C" void kernel_launch(void* const* d_in, const int* in_sizes, int n_in,
                              void* d_out, int out_size, void* d_ws, size_t ws_size,
                              hipStream_t stream) {
    (void)in_sizes; (void)n_in; (void)out_size; (void)ws_size;
    const float* q   = (const float*)d_in[0];
    const float* k   = (const float*)d_in[1];
    const float* Wf  = (const float*)d_in[2];
    const float* bf_ = (const float*)d_in[3];
    const float* fs  = (const float*)d_in[4];
    const float* fb  = (const float*)d_in[5];
    const float* fm  = (const float*)d_in[6];
    const float* fv  = (const float*)d_in[7];
    const float* Wg  = (const float*)d_in[8];
    const float* bg_ = (const float*)d_in[9];
    const float* gs  = (const float*)d_in[10];
    const float* gb  = (const float*)d_in[11];
    const float* gm  = (const float*)d_in[12];
    const float* gv  = (const float*)d_in[13];
    const float* Wh  = (const float*)d_in[14];
    const float* bh_ = (const float*)d_in[15];
    const float* hs  = (const float*)d_in[16];
    const float* hb  = (const float*)d_in[17];
    const float* hm  = (const float*)d_in[18];
    const float* hv  = (const float*)d_in[19];
    const float* gamma = (const float*)d_in[20];
    float* out = (float*)d_out;

    char* w = (char*)d_ws;
    _Float16* fT = (_Float16*)w;                               // 4 MB
    _Float16* gT = (_Float16*)(w + (size_t)4 * 1024 * 1024);   // 4 MB
    _Float16* hV = (_Float16*)(w + (size_t)8 * 1024 * 1024);   // 16 MB
    _Float16* Wfh = (_Float16*)(w + (size_t)24 * 1024 * 1024); // 32 KB
    _Float16* Wgh = Wfh + 16384;                               // 16 KB
    _Float16* Whh = Wgh + 8192;                                // 64 KB
    float* Af = (float*)(Whh + 32768);
    float* Bf = Af + 64;
    float* Ag = Bf + 64;
    float* Bg = Ag + 64;
    float* Ah = Bg + 64;
    float* Bh = Ah + 256;

    prep_kernel<<<128, 256, 0, stream>>>(Wf, Wg, Wh, bf_, fs, fb, fm, fv,
                                         bg_, gs, gb, gm, gv, bh_, hs, hb, hm, hv,
                                         Wfh, Wgh, Whh, Af, Bf, Ag, Bg, Ah, Bh);

    dim3 cgrid(NSEQ / 64, NB, 3);
    conv_fused<<<cgrid, 256, 0, stream>>>(q, k, Wfh, Wgh, Whh,
                                          Af, Bf, Ag, Bg, Ah, Bh, fT, gT, hV);

    attn_kernel<<<512, 256, 0, stream>>>(fT, gT, hV, q, gamma, out);
}